// Round 3
// baseline (223.714 us; speedup 1.0000x reference)
//
#include <hip/hip_runtime.h>

// Problem constants (B=4, N=M=8192, D=3)
#define NPTS   8192
#define BATCH  4
#define MSPLIT 16                // m-range splits per (b,dir)
#define QB     4                 // query tiles (32 queries each) per wave
#define TILES  (NPTS / 32)       // 256 point-tiles per (cloud,b)
#define TPB    (TILES / MSPLIT)  // 16 db tiles per wave
#define ITER   TPB               // one tile per inner iteration
#define NQTOT  (BATCH * 2 * NPTS)
#define NWAVES (64 * 8 * MSPLIT) // 8192 logical waves
#define WPB    4                 // waves per workgroup (beat the wg/CU cap)
#define NBLKM  (NWAVES / WPB)    // 2048 main blocks

typedef _Float16 f16x8  __attribute__((ext_vector_type(8)));
typedef float    f32x16 __attribute__((ext_vector_type(16)));

// ws layout (bytes):
//   TA  [8 bd][256 tile][64 lane] f16x8   @ 0         (2 MB)   db-role frags
//   QF  [8 bd][256 tile][64 lane] f16x8   @ 2 MB      (2 MB)   query-role frags
//   MIN8[8 bd][8192] uint (monotone enc)  @ 4 MB      (256 KB) atomicMin of true d2
//   CNT  uint                             @ 4.25 MB   (4 B)    last-block ticket
#define TA_OFF  0
#define QF_OFF  (2u << 20)
#define MIN_OFF (4u << 20)
#define CNT_OFF ((4u << 20) + (256u << 10))

// ---- Prepack: per point build hi/lo f16 split K-vectors in MFMA lane order.
// A (db role)   k = [th.x th.y th.z  th.x th.y th.z  tl.x tl.y | tl.z tl.x tl.y tl.z  hth htl 1   1  ]
// B (query role)k = [rh.x rh.y rh.z  rl.x rl.y rl.z  rh.x rh.y | rh.z rl.x rl.y rl.z  1   1   hqh hql]
// (r = -2q). Dot = (th+tl)·(rh+rl) + ht + hq ≈ |t|^2 - 2 q·t + |q|^2 = true d2.
// Also inits MIN8 to UINT_MAX (encoded +inf), zeroes ticket + out.
__global__ __launch_bounds__(256) void chamfer_prepack(
    const float* __restrict__ src, const float* __restrict__ tgt,
    f16x8* __restrict__ TA, f16x8* __restrict__ QF,
    unsigned* __restrict__ min8, unsigned* __restrict__ counter,
    float* __restrict__ out)
{
    int tid = blockIdx.x * 256 + threadIdx.x;      // (c*4+b)*8192 + pt
    if (tid == 0) { out[0] = 0.0f; *counter = 0u; }
    min8[tid] = 0xFFFFFFFFu;                       // init for atomicMin
    int c   = tid >> 15;
    int r   = tid & 32767;                         // b*8192 + pt
    const float* p = (c ? tgt : src) + (size_t)r * 3;
    float x = p[0], y = p[1], z = p[2];
    float h = x * x + y * y + z * z;

    _Float16 thx = (_Float16)x, thy = (_Float16)y, thz = (_Float16)z;
    _Float16 tlx = (_Float16)(x - (float)thx);
    _Float16 tly = (_Float16)(y - (float)thy);
    _Float16 tlz = (_Float16)(z - (float)thz);
    _Float16 hh  = (_Float16)h;
    _Float16 hl  = (_Float16)(h - (float)hh);

    float rx = -2.f * x, ry = -2.f * y, rz = -2.f * z;
    _Float16 rhx = (_Float16)rx, rhy = (_Float16)ry, rhz = (_Float16)rz;
    _Float16 rlx = (_Float16)(rx - (float)rhx);
    _Float16 rly = (_Float16)(ry - (float)rhy);
    _Float16 rlz = (_Float16)(rz - (float)rhz);

    int pt   = r & 8191;
    int bd   = tid >> 13;                          // c*4+b
    int tile = pt >> 5, ln = pt & 31;
    size_t base = ((size_t)bd * TILES + tile) * 64;

    _Float16 one = (_Float16)1.f;
    f16x8 alo = {thx, thy, thz, thx, thy, thz, tlx, tly};
    f16x8 ahi = {tlz, tlx, tly, tlz, hh,  hl,  one, one};
    TA[base + ln]      = alo;
    TA[base + 32 + ln] = ahi;
    f16x8 blo = {rhx, rhy, rhz, rlx, rly, rlz, rhx, rhy};
    f16x8 bhi = {rhz, rlx, rly, rlz, one, one, hh,  hl };
    QF[base + ln]      = blo;
    QF[base + 32 + ln] = bhi;
}

// min3 tree over the 16 C regs (rows = 16 of 32 db points; other half in lane^32)
__device__ __forceinline__ float red16(const f32x16& d) {
    float a = fminf(fminf(d[0],  d[1]),  d[2]);
    float b = fminf(fminf(d[3],  d[4]),  d[5]);
    float c = fminf(fminf(d[6],  d[7]),  d[8]);
    float e = fminf(fminf(d[9],  d[10]), d[11]);
    float f = fminf(fminf(d[12], d[13]), d[14]);
    float g = fminf(fminf(a, b), d[15]);
    float h = fminf(fminf(c, e), f);
    return fminf(g, h);
}

// Monotone float->uint encoding: preserves order for all finite floats.
__device__ __forceinline__ unsigned enc_f32(float x) {
    unsigned b = __float_as_uint(x);
    return (b & 0x80000000u) ? ~b : (b | 0x80000000u);
}
__device__ __forceinline__ float dec_f32(unsigned u) {
    unsigned b = (u & 0x80000000u) ? (u & 0x7FFFFFFFu) : ~u;
    return __uint_as_float(b);
}

// ---- Main: WPB=4 independent waves per 256-thread block; last-block-done
// trick folds the final reduction in (no grid.sync, no third dispatch).
// grid = 2048 blocks -> 8 blocks/CU -> 32 waves/CU (8/SIMD).
__global__ __launch_bounds__(256, 8) void chamfer_main(
    const f16x8* __restrict__ TA, const f16x8* __restrict__ QF,
    unsigned* __restrict__ min8, unsigned* __restrict__ counter,
    float* __restrict__ out)
{
    const int wid  = blockIdx.x * WPB + (threadIdx.x >> 6);  // logical wave id
    const int lane = threadIdx.x & 63;
    const int qw   = wid & 63;
    const int bd   = (wid >> 6) & 7;     // dir*4+b (queries from cloud=dir)
    const int ms   = wid >> 9;           // 0..MSPLIT-1
    const int bdT  = bd ^ 4;             // db side = opposite cloud

    f16x8 qf[QB];
    size_t qbase = ((size_t)bd * TILES + qw * QB) * 64 + lane;
    #pragma unroll
    for (int t = 0; t < QB; ++t) qf[t] = QF[qbase + t * 64];

    const f32x16 zero = {0.f,0.f,0.f,0.f,0.f,0.f,0.f,0.f,
                         0.f,0.f,0.f,0.f,0.f,0.f,0.f,0.f};
    float mn[QB];
    #pragma unroll
    for (int t = 0; t < QB; ++t) mn[t] = 3.0e38f;

    const size_t tbase = ((size_t)bdT * TILES + ms * TPB) * 64 + lane;

    // Software-pipelined: prefetch next tile while reducing current.
    f16x8 a = TA[tbase];
    for (int i = 0; i < ITER - 1; ++i) {
        f16x8 n = TA[tbase + (size_t)(i + 1) * 64];
        #pragma unroll
        for (int t = 0; t < QB; ++t) {
            f32x16 d = __builtin_amdgcn_mfma_f32_32x32x16_f16(a, qf[t], zero, 0, 0, 0);
            mn[t] = fminf(mn[t], red16(d));
        }
        a = n;
    }
    #pragma unroll
    for (int t = 0; t < QB; ++t) {
        f32x16 d = __builtin_amdgcn_mfma_f32_32x32x16_f16(a, qf[t], zero, 0, 0, 0);
        mn[t] = fminf(mn[t], red16(d));
    }

    // Each lane covered 16 of 32 rows per tile; other 16 rows are in lane^32.
    #pragma unroll
    for (int t = 0; t < QB; ++t) mn[t] = fminf(mn[t], __shfl_xor(mn[t], 32));

    // Cross-ms combine: device-scope atomic umin on encoded true-d2 floats.
    if (lane < 32) {
        unsigned* basep = min8 + (size_t)bd * NPTS + qw * (QB * 32) + lane;
        #pragma unroll
        for (int t = 0; t < QB; ++t) atomicMin(basep + t * 32, enc_f32(mn[t]));
    }

    // ---- Last-block-done final reduction (rocPRIM idiom) ----
    __threadfence();                     // release our atomics device-wide
    __syncthreads();                     // all waves of this block done
    __shared__ int is_last;
    if (threadIdx.x == 0)
        is_last = (atomicAdd(counter, 1u) == NBLKM - 1);
    __syncthreads();
    if (!is_last) return;

    __threadfence();                     // acquire: see all blocks' mins
    float acc = 0.f;
    #pragma unroll 4
    for (int i = threadIdx.x; i < NQTOT; i += 256) {
        unsigned u = __hip_atomic_load(min8 + i, __ATOMIC_RELAXED,
                                       __HIP_MEMORY_SCOPE_AGENT);
        acc += dec_f32(u);
    }
    #pragma unroll
    for (int off = 32; off > 0; off >>= 1) acc += __shfl_down(acc, off);
    __shared__ float sdata[4];
    if ((threadIdx.x & 63) == 0) sdata[threadIdx.x >> 6] = acc;
    __syncthreads();
    if (threadIdx.x == 0)
        out[0] = ((sdata[0] + sdata[1]) + (sdata[2] + sdata[3]))
               * (1.0f / (float)(BATCH * NPTS));
}

extern "C" void kernel_launch(void* const* d_in, const int* in_sizes, int n_in,
                              void* d_out, int out_size, void* d_ws, size_t ws_size,
                              hipStream_t stream) {
    const float* src = (const float*)d_in[0];   // (B, N, 3) fp32
    const float* tgt = (const float*)d_in[1];   // (B, M, 3) fp32
    float* out = (float*)d_out;

    f16x8*    TA   = (f16x8*)((char*)d_ws + TA_OFF);
    f16x8*    QF   = (f16x8*)((char*)d_ws + QF_OFF);
    unsigned* MIN8 = (unsigned*)((char*)d_ws + MIN_OFF);
    unsigned* CNT  = (unsigned*)((char*)d_ws + CNT_OFF);

    chamfer_prepack<<<NQTOT / 256, 256, 0, stream>>>(src, tgt, TA, QF, MIN8, CNT, out);
    chamfer_main<<<NWAVES / WPB, 256, 0, stream>>>(TA, QF, MIN8, CNT, out);
}

// Round 4
// 80.437 us; speedup vs baseline: 2.7812x; 2.7812x over previous
//
#include <hip/hip_runtime.h>

// Problem constants (B=4, N=M=8192, D=3)
#define NPTS   8192
#define BATCH  4
#define MSPLIT 16                // m-range splits per (b,dir)
#define QB     8                 // query tiles (32 queries each) per wave
#define QWN    (NPTS / 32 / QB)  // 32 query-groups per (bd)
#define TILES  (NPTS / 32)       // 256 point-tiles per (cloud,b)
#define TPB    (TILES / MSPLIT)  // 16 db tiles per wave
#define ITER   TPB               // one tile per inner iteration
#define NQTOT  (BATCH * 2 * NPTS)
#define NWAVES (QWN * 8 * MSPLIT) // 4096 logical waves
#define WPB    4                 // waves per workgroup
#define NBLKM  (NWAVES / WPB)    // 1024 main blocks

typedef _Float16 f16x8  __attribute__((ext_vector_type(8)));
typedef float    f32x16 __attribute__((ext_vector_type(16)));

// ws layout (bytes):
//   TA  [8 bd][256 tile][64 lane] f16x8   @ 0         (2 MB)   db-role frags
//   QF  [8 bd][256 tile][64 lane] f16x8   @ 2 MB      (2 MB)   query-role frags
//   MIN8[8 bd][8192] uint (monotone enc)  @ 4 MB      (256 KB) atomicMin of true d2
#define TA_OFF  0
#define QF_OFF  (2u << 20)
#define MIN_OFF (4u << 20)

// ---- Prepack: per point build hi/lo f16 split K-vectors in MFMA lane order.
// A (db role)   k = [th.x th.y th.z  th.x th.y th.z  tl.x tl.y | tl.z tl.x tl.y tl.z  hth htl 1   1  ]
// B (query role)k = [rh.x rh.y rh.z  rl.x rl.y rl.z  rh.x rh.y | rh.z rl.x rl.y rl.z  1   1   hqh hql]
// (r = -2q). Dot = (th+tl)·(rh+rl) + ht + hq ≈ |t|^2 - 2 q·t + |q|^2 = true d2.
// (validated in R3: absmax 0.0). Also inits MIN8 to encoded +inf, zeroes out.
__global__ __launch_bounds__(256) void chamfer_prepack(
    const float* __restrict__ src, const float* __restrict__ tgt,
    f16x8* __restrict__ TA, f16x8* __restrict__ QF,
    unsigned* __restrict__ min8, float* __restrict__ out)
{
    int tid = blockIdx.x * 256 + threadIdx.x;      // (c*4+b)*8192 + pt
    if (tid == 0) out[0] = 0.0f;
    min8[tid] = 0xFFFFFFFFu;                       // init for atomicMin
    int c   = tid >> 15;
    int r   = tid & 32767;                         // b*8192 + pt
    const float* p = (c ? tgt : src) + (size_t)r * 3;
    float x = p[0], y = p[1], z = p[2];
    float h = x * x + y * y + z * z;

    _Float16 thx = (_Float16)x, thy = (_Float16)y, thz = (_Float16)z;
    _Float16 tlx = (_Float16)(x - (float)thx);
    _Float16 tly = (_Float16)(y - (float)thy);
    _Float16 tlz = (_Float16)(z - (float)thz);
    _Float16 hh  = (_Float16)h;
    _Float16 hl  = (_Float16)(h - (float)hh);

    float rx = -2.f * x, ry = -2.f * y, rz = -2.f * z;
    _Float16 rhx = (_Float16)rx, rhy = (_Float16)ry, rhz = (_Float16)rz;
    _Float16 rlx = (_Float16)(rx - (float)rhx);
    _Float16 rly = (_Float16)(ry - (float)rhy);
    _Float16 rlz = (_Float16)(rz - (float)rhz);

    int pt   = r & 8191;
    int bd   = tid >> 13;                          // c*4+b
    int tile = pt >> 5, ln = pt & 31;
    size_t base = ((size_t)bd * TILES + tile) * 64;

    _Float16 one = (_Float16)1.f;
    f16x8 alo = {thx, thy, thz, thx, thy, thz, tlx, tly};
    f16x8 ahi = {tlz, tlx, tly, tlz, hh,  hl,  one, one};
    TA[base + ln]      = alo;
    TA[base + 32 + ln] = ahi;
    f16x8 blo = {rhx, rhy, rhz, rlx, rly, rlz, rhx, rhy};
    f16x8 bhi = {rhz, rlx, rly, rlz, one, one, hh,  hl };
    QF[base + ln]      = blo;
    QF[base + 32 + ln] = bhi;
}

// min3 tree over the 16 C regs (rows = 16 of 32 db points; other half in lane^32)
__device__ __forceinline__ float red16(const f32x16& d) {
    float a = fminf(fminf(d[0],  d[1]),  d[2]);
    float b = fminf(fminf(d[3],  d[4]),  d[5]);
    float c = fminf(fminf(d[6],  d[7]),  d[8]);
    float e = fminf(fminf(d[9],  d[10]), d[11]);
    float f = fminf(fminf(d[12], d[13]), d[14]);
    float g = fminf(fminf(a, b), d[15]);
    float h = fminf(fminf(c, e), f);
    return fminf(g, h);
}

// Monotone float->uint encoding: preserves order for all finite floats.
__device__ __forceinline__ unsigned enc_f32(float x) {
    unsigned b = __float_as_uint(x);
    return (b & 0x80000000u) ? ~b : (b | 0x80000000u);
}
__device__ __forceinline__ float dec_f32(unsigned u) {
    unsigned b = (u & 0x80000000u) ? (u & 0x7FFFFFFFu) : ~u;
    return __uint_as_float(b);
}

// ---- Main: QB=8 (256 queries/wave) halves wave count and TA traffic vs QB=4;
// compute per loaded tile (~208 SIMD-cyc) now exceeds L2 latency, so 4 waves/
// SIMD suffice. 2-deep prefetch keeps 2 loads in flight (vmcnt(1) waits).
// grid = 1024 blocks -> 4 blocks/CU -> 16 waves/CU. NO device fences (R3 lesson).
__global__ __launch_bounds__(256, 4) void chamfer_main(
    const f16x8* __restrict__ TA, const f16x8* __restrict__ QF,
    unsigned* __restrict__ min8)
{
    const int wid  = blockIdx.x * WPB + (threadIdx.x >> 6);  // logical wave id
    const int lane = threadIdx.x & 63;
    const int qw   = wid & (QWN - 1);    // 0..31 query group
    const int bd   = (wid >> 5) & 7;     // dir*4+b (queries from cloud=dir)
    const int ms   = wid >> 8;           // 0..MSPLIT-1
    const int bdT  = bd ^ 4;             // db side = opposite cloud

    f16x8 qf[QB];
    size_t qbase = ((size_t)bd * TILES + qw * QB) * 64 + lane;
    #pragma unroll
    for (int t = 0; t < QB; ++t) qf[t] = QF[qbase + t * 64];

    const f32x16 zero = {0.f,0.f,0.f,0.f,0.f,0.f,0.f,0.f,
                         0.f,0.f,0.f,0.f,0.f,0.f,0.f,0.f};
    float mn[QB];
    #pragma unroll
    for (int t = 0; t < QB; ++t) mn[t] = 3.0e38f;

    const size_t tbase = ((size_t)bdT * TILES + ms * TPB) * 64 + lane;

    // 2-deep software pipeline: tiles i+1, i+2 in flight while computing i.
    f16x8 a = TA[tbase];
    f16x8 n = TA[tbase + 64];
    for (int i = 0; i < ITER - 2; ++i) {
        f16x8 n2 = TA[tbase + (size_t)(i + 2) * 64];
        #pragma unroll
        for (int t = 0; t < QB; ++t) {
            f32x16 d = __builtin_amdgcn_mfma_f32_32x32x16_f16(a, qf[t], zero, 0, 0, 0);
            mn[t] = fminf(mn[t], red16(d));
        }
        a = n; n = n2;
    }
    #pragma unroll
    for (int t = 0; t < QB; ++t) {
        f32x16 d = __builtin_amdgcn_mfma_f32_32x32x16_f16(a, qf[t], zero, 0, 0, 0);
        mn[t] = fminf(mn[t], red16(d));
    }
    #pragma unroll
    for (int t = 0; t < QB; ++t) {
        f32x16 d = __builtin_amdgcn_mfma_f32_32x32x16_f16(n, qf[t], zero, 0, 0, 0);
        mn[t] = fminf(mn[t], red16(d));
    }

    // Each lane covered 16 of 32 rows per tile; other 16 rows are in lane^32.
    #pragma unroll
    for (int t = 0; t < QB; ++t) mn[t] = fminf(mn[t], __shfl_xor(mn[t], 32));

    // Cross-ms combine: device-scope atomic umin on encoded true-d2 floats
    // (fire-and-forget; no fence needed — ordering comes from kernel boundary).
    if (lane < 32) {
        unsigned* basep = min8 + (size_t)bd * NPTS + qw * (QB * 32) + lane;
        #pragma unroll
        for (int t = 0; t < QB; ++t) atomicMin(basep + t * 32, enc_f32(mn[t]));
    }
}

// ---- Reduce: decode min (already true d2 incl. |q|^2), sum, scale ----
__global__ __launch_bounds__(256) void chamfer_reduce(
    const unsigned* __restrict__ min8, float* __restrict__ out)
{
    const int q = blockIdx.x * 256 + threadIdx.x;   // bd*8192 + n
    float acc = dec_f32(min8[q]);
    #pragma unroll
    for (int off = 32; off > 0; off >>= 1) acc += __shfl_down(acc, off);

    __shared__ float sdata[4];
    if ((threadIdx.x & 63) == 0) sdata[threadIdx.x >> 6] = acc;
    __syncthreads();
    if (threadIdx.x == 0) {
        float t = (sdata[0] + sdata[1]) + (sdata[2] + sdata[3]);
        atomicAdd(out, t * (1.0f / (float)(BATCH * NPTS)));
    }
}

extern "C" void kernel_launch(void* const* d_in, const int* in_sizes, int n_in,
                              void* d_out, int out_size, void* d_ws, size_t ws_size,
                              hipStream_t stream) {
    const float* src = (const float*)d_in[0];   // (B, N, 3) fp32
    const float* tgt = (const float*)d_in[1];   // (B, M, 3) fp32
    float* out = (float*)d_out;

    f16x8*    TA   = (f16x8*)((char*)d_ws + TA_OFF);
    f16x8*    QF   = (f16x8*)((char*)d_ws + QF_OFF);
    unsigned* MIN8 = (unsigned*)((char*)d_ws + MIN_OFF);

    chamfer_prepack<<<NQTOT / 256, 256, 0, stream>>>(src, tgt, TA, QF, MIN8, out);
    chamfer_main<<<NBLKM, 256, 0, stream>>>(TA, QF, MIN8);
    chamfer_reduce<<<NQTOT / 256, 256, 0, stream>>>(MIN8, out);
}